// Round 18
// baseline (1719.422 us; speedup 1.0000x reference)
//
#include <hip/hip_runtime.h>
#include <stdint.h>

#define B_ROWS 16384
#define NIN    784
#define NH     500
#define NHP    512
#define NOUT   10
#define STEPS  25

// Verified reference semantics (R15 PASS):
//   fc1: per (row,n): f32 fmaf chains ascending k, k-blocks [0,512)+[512,784),
//        combined by one __fadd_rn; + b1 via one __fadd_rn.
//   LIF (both layers), per-op f32: m = fsub(fadd(fmul(0.95f,m),c),reset); spike = m>1
//   fc2: ascending-h conditional fadd chain (== fmaf(bit,w,acc)), + b2, LIF2.

// ---------------- K1: fc1 + LIF1 -> masks ----------------
// 16 rows/block (4/wave); lane owns units {lane+64j}. w1 double-buffered in LDS,
// odd-stride 17 layout (conflict-minimal b128). T14 staging: global->reg loads
// issued BEFORE compute, ds_write after, 1 barrier/chunk.

#define KT   16
#define NCH  49       // 784/16
#define CHSPL 32      // chunks [0,32) -> k<512 (BLIS block 1)
#define WSTR 17       // LDS unit stride (floats)

#define K1_LOAD(c_next)                                                        \
    {                                                                          \
        const int k0n = (c_next) * KT;                                         \
        _Pragma("unroll")                                                      \
        for (int s = 0; s < 8; ++s) {                                          \
            const int i = t + 256 * s;                                         \
            const int u = i >> 2, q = i & 3;                                   \
            if (u < NH) sreg[s] = *(const float4*)(w1 + (size_t)u * NIN + k0n + q * 4); \
        }                                                                      \
    }

#define K1_WRITE(c_next)                                                       \
    {                                                                          \
        float* wb = wt[(c_next) & 1];                                          \
        _Pragma("unroll")                                                      \
        for (int s = 0; s < 8; ++s) {                                          \
            const int i = t + 256 * s;                                         \
            const int u = i >> 2, q = i & 3;                                   \
            if (u < NH) *(float4*)&wb[u * WSTR + q * 4] = sreg[s];             \
        }                                                                      \
    }

#define K1_COMPUTE(c, acc)                                                     \
    {                                                                          \
        const float* wbuf = wt[(c) & 1];                                       \
        const int k0 = (c) * KT;                                               \
        _Pragma("unroll")                                                      \
        for (int q = 0; q < 4; ++q) {                                          \
            float4 xq[4];                                                      \
            _Pragma("unroll")                                                  \
            for (int r = 0; r < 4; ++r)                                        \
                xq[r] = *(const float4*)(x + (size_t)(row0 + r) * NIN + k0 + q * 4); \
            _Pragma("unroll")                                                  \
            for (int j = 0; j < 8; ++j) {                                      \
                const float4 wv = *(const float4*)&wbuf[(64 * j + lane) * WSTR + q * 4]; \
                _Pragma("unroll")                                              \
                for (int r = 0; r < 4; ++r) {                                  \
                    acc[j][r] = fmaf(xq[r].x, wv.x, acc[j][r]);                \
                    acc[j][r] = fmaf(xq[r].y, wv.y, acc[j][r]);                \
                    acc[j][r] = fmaf(xq[r].z, wv.z, acc[j][r]);                \
                    acc[j][r] = fmaf(xq[r].w, wv.w, acc[j][r]);                \
                }                                                              \
            }                                                                  \
        }                                                                      \
    }

__global__ __launch_bounds__(256) void k1_fc1(
    const float* __restrict__ x, const float* __restrict__ w1,
    const float* __restrict__ b1, uint32_t* __restrict__ masks_g)
{
    __shared__ float wt[2][NHP * WSTR];     // 2 x 34,816 B
    const int t    = threadIdx.x;
    const int lane = t & 63;
    const int row0 = blockIdx.x * 16 + (t >> 6) * 4;

    float4 sreg[8];
    float accA[8][4], accB[8][4];
#pragma unroll
    for (int j = 0; j < 8; ++j)
#pragma unroll
        for (int r = 0; r < 4; ++r) { accA[j][r] = 0.f; accB[j][r] = 0.f; }

    // prologue: stage chunk 0
    K1_LOAD(0); K1_WRITE(0);
    __syncthreads();

    for (int c = 0; c < CHSPL; ++c) {       // k in [0,512) -> accA
        K1_LOAD(c + 1);
        K1_COMPUTE(c, accA);
        K1_WRITE(c + 1);
        __syncthreads();
    }
    for (int c = CHSPL; c < NCH - 1; ++c) { // k in [512,768) -> accB
        K1_LOAD(c + 1);
        K1_COMPUTE(c, accB);
        K1_WRITE(c + 1);
        __syncthreads();
    }
    K1_COMPUTE(NCH - 1, accB);              // last chunk [768,784)

#pragma unroll
    for (int j = 0; j < 8; ++j) {
        const int u = 64 * j + lane;
        if (u >= NH) continue;
        const float bb = b1[u];
#pragma unroll
        for (int r = 0; r < 4; ++r) {
            const float dot = __fadd_rn(accA[j][r], accB[j][r]);  // combine blocks
            const float c   = __fadd_rn(dot, bb);                 // + bias
            float m = 0.f;
            uint32_t bits = 0;
#pragma unroll
            for (int st = 0; st < STEPS; ++st) {
                const float rs = (m > 1.0f) ? 1.0f : 0.0f;        // reset from PREV mem
                m = __fsub_rn(__fadd_rn(__fmul_rn(0.95f, m), c), rs);
                bits |= ((m > 1.0f) ? 1u : 0u) << st;
            }
            masks_g[(size_t)(row0 + r) * NHP + u] = bits;
        }
    }
}

// ---------------- K2: fc2 + LIF2 -> outputs ----------------
// Masks read from GLOBAL (10-lane broadcast, L1/L2) -- no LDS bank issue.
// Only w2^T (20 KB) in LDS. fmaf(bit,w,acc) == reference conditional fadd.

#define K2_RPB 25

__global__ __launch_bounds__(256) void k2_fc2(
    const uint32_t* __restrict__ masks_g, const float* __restrict__ w2,
    const float* __restrict__ b2, float* __restrict__ out)
{
    __shared__ float w2s[NH][NOUT];          // 20,000 B
    __shared__ float b2s[NOUT];

    const int t    = threadIdx.x;
    const int row0 = blockIdx.x * K2_RPB;

    for (int i = t; i < NH * NOUT; i += 256) {
        const int h = i / NOUT, o = i - h * NOUT;
        w2s[h][o] = w2[o * NH + h];
    }
    if (t < NOUT) b2s[t] = b2[t];
    __syncthreads();

    const int r = t / NOUT;
    const int o = t - r * NOUT;
    const int row = row0 + r;
    if (t >= K2_RPB * NOUT || row >= B_ROWS) return;

    float a[STEPS];
#pragma unroll
    for (int st = 0; st < STEPS; ++st) a[st] = 0.f;

    const uint32_t* mrow = masks_g + (size_t)row * NHP;
    for (int h = 0; h < NH; ++h) {
        const uint32_t mw = mrow[h];
        const float wv = w2s[h][o];
#pragma unroll
        for (int st = 0; st < STEPS; ++st) {
            const float s = (float)((mw >> st) & 1u);
            a[st] = fmaf(s, wv, a[st]);              // ascending-h chain, exact
        }
    }

    float* spk_out = out;
    float* mem_out = out + (size_t)STEPS * B_ROWS * NOUT;
    const size_t base = (size_t)row * NOUT + o;
    const float bo = b2s[o];
    float m = 0.f;
#pragma unroll
    for (int st = 0; st < STEPS; ++st) {
        const float c  = __fadd_rn(a[st], bo);
        const float rs = (m > 1.0f) ? 1.0f : 0.0f;
        m = __fsub_rn(__fadd_rn(__fmul_rn(0.95f, m), c), rs);
        const size_t idx = (size_t)st * (B_ROWS * NOUT) + base;
        spk_out[idx] = (m > 1.0f) ? 1.0f : 0.0f;
        mem_out[idx] = m;
    }
}

extern "C" void kernel_launch(void* const* d_in, const int* in_sizes, int n_in,
                              void* d_out, int out_size, void* d_ws, size_t ws_size,
                              hipStream_t stream)
{
    const float* x  = (const float*)d_in[0];
    const float* w1 = (const float*)d_in[1];
    const float* b1 = (const float*)d_in[2];
    const float* w2 = (const float*)d_in[3];
    const float* b2 = (const float*)d_in[4];
    float* out = (float*)d_out;

    uint32_t* masks_g = (uint32_t*)d_ws;     // 33,554,432 B

    k1_fc1<<<dim3(B_ROWS / 16), 256, 0, stream>>>(x, w1, b1, masks_g);
    k2_fc2<<<dim3((B_ROWS + K2_RPB - 1) / K2_RPB), 256, 0, stream>>>(masks_g, w2, b2, out);
}

// Round 19
// 786.482 us; speedup vs baseline: 2.1862x; 2.1862x over previous
//
#include <hip/hip_runtime.h>
#include <stdint.h>

#define B_ROWS 16384
#define NIN    784
#define NH     500
#define NOUT   10
#define STEPS  25

// Verified reference semantics (R15 PASS):
//   fc1: per (row,n): f32 fmaf chains ascending k, k-blocks [0,512)+[512,784),
//        combined by one __fadd_rn; + b1 via one __fadd_rn.
//   LIF (both layers), per-op f32: m = fsub(fadd(fmul(0.95f,m),c),reset); spike = m>1
//   fc2: ascending-h conditional fadd chain (== fmaf(bit,w,acc)), + b2, LIF2.

// ---------------- K1: fc1 + LIF1 -> masks[unit][row] ----------------
// Block: 256 threads = 256 rows (lane = row); 25 units, block-uniform ->
// w1 reads become SCALAR loads (s_load), no w staging. x double-buffered in
// LDS (stride-18 rows, conflict-free b64 reads), 1 barrier/chunk, loads
// issued before compute. acc[2][25] = exact BLIS [512|272] split.

#define RPBK1  256
#define UPB    25      // 500 = 20 blocks x 25 units
#define KC     16
#define NCHK   49      // 784/16
#define SPLITC 32      // chunks [0,32) -> k<512
#define XSTR   18      // xs row stride (floats); 72B rows -> 8B aligned, 2-way banks

#define LOADX(c)                                                               \
    {                                                                          \
        const int k0n = (c) * KC;                                              \
        _Pragma("unroll")                                                      \
        for (int s = 0; s < 4; ++s) {                                          \
            const int idx = s * 256 + t;                                       \
            const int rl = idx >> 2, kq = idx & 3;                             \
            lreg[s] = *(const float4*)(x + (size_t)(row0 + rl) * NIN + k0n + kq * 4); \
        }                                                                      \
    }

#define WRITEX(c)                                                              \
    {                                                                          \
        float* xb = xs[(c) & 1];                                               \
        _Pragma("unroll")                                                      \
        for (int s = 0; s < 4; ++s) {                                          \
            const int idx = s * 256 + t;                                       \
            const int rl = idx >> 2, kq = idx & 3;                             \
            float2* p = (float2*)&xb[rl * XSTR + kq * 4];                      \
            p[0] = make_float2(lreg[s].x, lreg[s].y);                          \
            p[1] = make_float2(lreg[s].z, lreg[s].w);                          \
        }                                                                      \
    }

#define COMPUTE(c, acc)                                                        \
    {                                                                          \
        const float* xb = xs[(c) & 1];                                         \
        const int k0c = (c) * KC;                                              \
        _Pragma("unroll")                                                      \
        for (int kh = 0; kh < KC / 2; ++kh) {                                  \
            const float2 xv = *(const float2*)&xb[t * XSTR + kh * 2];          \
            _Pragma("unroll")                                                  \
            for (int j = 0; j < UPB; ++j) {                                    \
                const float* wp = w1 + (size_t)(u0 + j) * NIN + k0c + kh * 2;  \
                acc[j] = fmaf(xv.x, wp[0], acc[j]);   /* ascending k */        \
                acc[j] = fmaf(xv.y, wp[1], acc[j]);                            \
            }                                                                  \
        }                                                                      \
    }

__global__ __launch_bounds__(256) void k1_fc1(
    const float* __restrict__ x, const float* __restrict__ w1,
    const float* __restrict__ b1, uint32_t* __restrict__ masks_g)
{
    __shared__ float xs[2][RPBK1 * XSTR];   // 2 x 18,432 B

    // XCD swizzle: 1280 blocks = 8 XCD x 160; same row-slice's 20 unit-blocks
    // land consecutively on one XCD (x slice stays L2-resident).
    const int orig = blockIdx.x;
    const int wid  = (orig & 7) * 160 + (orig >> 3);
    const int rowblk = wid / 20;
    const int ug     = wid - rowblk * 20;
    const int row0 = rowblk * RPBK1;
    const int u0   = ug * UPB;              // block-uniform -> scalar w1 loads
    const int t    = threadIdx.x;
    const int row  = row0 + t;

    float4 lreg[4];
    float accA[UPB], accB[UPB];
#pragma unroll
    for (int j = 0; j < UPB; ++j) { accA[j] = 0.f; accB[j] = 0.f; }

    LOADX(0); WRITEX(0);
    __syncthreads();

    for (int c = 0; c < SPLITC; ++c) {          // k in [0,512) -> accA
        LOADX(c + 1);
        COMPUTE(c, accA);
        WRITEX(c + 1);
        __syncthreads();
    }
    for (int c = SPLITC; c < NCHK - 1; ++c) {   // k in [512,768) -> accB
        LOADX(c + 1);
        COMPUTE(c, accB);
        WRITEX(c + 1);
        __syncthreads();
    }
    COMPUTE(NCHK - 1, accB);                    // k in [768,784)

#pragma unroll
    for (int j = 0; j < UPB; ++j) {
        const int u = u0 + j;
        const float dot = __fadd_rn(accA[j], accB[j]);   // combine blocks
        const float c   = __fadd_rn(dot, b1[u]);         // + bias (scalar load)
        float m = 0.f;
        uint32_t bits = 0;
#pragma unroll
        for (int st = 0; st < STEPS; ++st) {
            const float rs = (m > 1.0f) ? 1.0f : 0.0f;   // reset from PREV mem
            m = __fsub_rn(__fadd_rn(__fmul_rn(0.95f, m), c), rs);
            bits |= ((m > 1.0f) ? 1u : 0u) << st;
        }
        masks_g[(size_t)u * B_ROWS + row] = bits;        // coalesced (lane=row)
    }
}

// ---------------- K2: fc2 + LIF2 -> outputs ----------------
// Masks in [unit][row] layout: per h, 25 block-rows span ~100B -> L1-friendly.
#define K2_RPB 25

__global__ __launch_bounds__(256) void k2_fc2(
    const uint32_t* __restrict__ masks_g, const float* __restrict__ w2,
    const float* __restrict__ b2, float* __restrict__ out)
{
    __shared__ float w2s[NH][NOUT];          // 20,000 B
    __shared__ float b2s[NOUT];

    const int t    = threadIdx.x;
    const int row0 = blockIdx.x * K2_RPB;

    for (int i = t; i < NH * NOUT; i += 256) {
        const int h = i / NOUT, o = i - h * NOUT;
        w2s[h][o] = w2[o * NH + h];
    }
    if (t < NOUT) b2s[t] = b2[t];
    __syncthreads();

    const int r = t / NOUT;
    const int o = t - r * NOUT;
    const int row = row0 + r;
    if (t >= K2_RPB * NOUT || row >= B_ROWS) return;

    float a[STEPS];
#pragma unroll
    for (int st = 0; st < STEPS; ++st) a[st] = 0.f;

    for (int h = 0; h < NH; ++h) {
        const uint32_t mw = masks_g[(size_t)h * B_ROWS + row];
        const float wv = w2s[h][o];
#pragma unroll
        for (int st = 0; st < STEPS; ++st) {
            const float s = (float)((mw >> st) & 1u);
            a[st] = fmaf(s, wv, a[st]);              // ascending-h chain, exact
        }
    }

    float* spk_out = out;
    float* mem_out = out + (size_t)STEPS * B_ROWS * NOUT;
    const size_t base = (size_t)row * NOUT + o;
    const float bo = b2s[o];
    float m = 0.f;
#pragma unroll
    for (int st = 0; st < STEPS; ++st) {
        const float c  = __fadd_rn(a[st], bo);
        const float rs = (m > 1.0f) ? 1.0f : 0.0f;
        m = __fsub_rn(__fadd_rn(__fmul_rn(0.95f, m), c), rs);
        const size_t idx = (size_t)st * (B_ROWS * NOUT) + base;
        spk_out[idx] = (m > 1.0f) ? 1.0f : 0.0f;
        mem_out[idx] = m;
    }
}

extern "C" void kernel_launch(void* const* d_in, const int* in_sizes, int n_in,
                              void* d_out, int out_size, void* d_ws, size_t ws_size,
                              hipStream_t stream)
{
    const float* x  = (const float*)d_in[0];
    const float* w1 = (const float*)d_in[1];
    const float* b1 = (const float*)d_in[2];
    const float* w2 = (const float*)d_in[3];
    const float* b2 = (const float*)d_in[4];
    float* out = (float*)d_out;

    uint32_t* masks_g = (uint32_t*)d_ws;     // 500*16384*4 = 32,768,000 B

    k1_fc1<<<dim3((B_ROWS / RPBK1) * 20), 256, 0, stream>>>(x, w1, b1, masks_g);
    k2_fc2<<<dim3((B_ROWS + K2_RPB - 1) / K2_RPB), 256, 0, stream>>>(masks_g, w2, b2, out);
}

// Round 20
// 326.327 us; speedup vs baseline: 5.2690x; 2.4101x over previous
//
#include <hip/hip_runtime.h>
#include <stdint.h>

#define B_ROWS 16384
#define NIN    784
#define NH     500
#define NHP    512
#define NOUT   10
#define STEPS  25

// Verified reference semantics (R15 PASS):
//   fc1: per (row,n): f32 fmaf chains ascending k, k-blocks [0,512)+[512,784),
//        combined by one __fadd_rn; + b1 via one __fadd_rn.
//   LIF (both layers), per-op f32: m = fsub(fadd(fmul(0.95f,m),c),reset); spike = m>1
//   fc2: single ascending-h conditional-fadd chain (== fmaf(bit,w,acc)), + b2, LIF2.

// ---------------- K0: w1[500][784] -> k-blocked w1tb[k/4][512][4] ----------------
__global__ __launch_bounds__(256) void k0_wtrans(
    const float* __restrict__ w1, float* __restrict__ w1tb)
{
    const int i  = blockIdx.x * 256 + threadIdx.x;   // 512*196 total
    const int u  = i & 511;
    const int kb = i >> 9;
    if (kb >= 196) return;
    float4 v = make_float4(0.f, 0.f, 0.f, 0.f);
    if (u < NH) v = *(const float4*)(w1 + (size_t)u * NIN + kb * 4);
    *(float4*)(w1tb + (size_t)kb * 2048 + u * 4) = v;   // coalesced over u
}

// ---------------- K1: fc1 + LIF1 -> masks[row][512] ----------------
// lane = unit (t and t+256); rows block-uniform -> x via SCALAR loads.
// No LDS, no barriers. w loads: coalesced float4 (vmcnt). acc A/B = BLIS split.

#define K1_R 16

__global__ __launch_bounds__(256) void k1_fc1(
    const float* __restrict__ x, const float* __restrict__ w1tb,
    const float* __restrict__ b1, uint32_t* __restrict__ masks_g)
{
    const int t    = threadIdx.x;
    const int row0 = blockIdx.x * K1_R;

    float accA[2][K1_R], accB[2][K1_R];
#pragma unroll
    for (int u = 0; u < 2; ++u)
#pragma unroll
        for (int r = 0; r < K1_R; ++r) { accA[u][r] = 0.f; accB[u][r] = 0.f; }

    // phase A: k in [0,512)  (BLIS block 1), kb = 0..127
    for (int kb = 0; kb < 128; ++kb) {
        const float4 wv0 = *(const float4*)(w1tb + (size_t)kb * 2048 + t * 4);
        const float4 wv1 = *(const float4*)(w1tb + (size_t)kb * 2048 + (t + 256) * 4);
#pragma unroll
        for (int r = 0; r < K1_R; ++r) {
            const float* xr = x + (size_t)(row0 + r) * NIN + kb * 4;  // uniform -> s_load
            const float x0 = xr[0], x1 = xr[1], x2 = xr[2], x3 = xr[3];
            accA[0][r] = fmaf(x0, wv0.x, accA[0][r]);   // ascending k per chain
            accA[0][r] = fmaf(x1, wv0.y, accA[0][r]);
            accA[0][r] = fmaf(x2, wv0.z, accA[0][r]);
            accA[0][r] = fmaf(x3, wv0.w, accA[0][r]);
            accA[1][r] = fmaf(x0, wv1.x, accA[1][r]);
            accA[1][r] = fmaf(x1, wv1.y, accA[1][r]);
            accA[1][r] = fmaf(x2, wv1.z, accA[1][r]);
            accA[1][r] = fmaf(x3, wv1.w, accA[1][r]);
        }
    }
    // phase B: k in [512,784), kb = 128..195
    for (int kb = 128; kb < 196; ++kb) {
        const float4 wv0 = *(const float4*)(w1tb + (size_t)kb * 2048 + t * 4);
        const float4 wv1 = *(const float4*)(w1tb + (size_t)kb * 2048 + (t + 256) * 4);
#pragma unroll
        for (int r = 0; r < K1_R; ++r) {
            const float* xr = x + (size_t)(row0 + r) * NIN + kb * 4;
            const float x0 = xr[0], x1 = xr[1], x2 = xr[2], x3 = xr[3];
            accB[0][r] = fmaf(x0, wv0.x, accB[0][r]);
            accB[0][r] = fmaf(x1, wv0.y, accB[0][r]);
            accB[0][r] = fmaf(x2, wv0.z, accB[0][r]);
            accB[0][r] = fmaf(x3, wv0.w, accB[0][r]);
            accB[1][r] = fmaf(x0, wv1.x, accB[1][r]);
            accB[1][r] = fmaf(x1, wv1.y, accB[1][r]);
            accB[1][r] = fmaf(x2, wv1.z, accB[1][r]);
            accB[1][r] = fmaf(x3, wv1.w, accB[1][r]);
        }
    }

#pragma unroll
    for (int uu = 0; uu < 2; ++uu) {
        const int u = t + uu * 256;
        if (u >= NH) continue;
        const float bb = b1[u];
#pragma unroll
        for (int r = 0; r < K1_R; ++r) {
            const float dot = __fadd_rn(accA[uu][r], accB[uu][r]);  // combine blocks
            const float c   = __fadd_rn(dot, bb);                   // + bias
            float m = 0.f;
            uint32_t bits = 0;
#pragma unroll
            for (int st = 0; st < STEPS; ++st) {
                const float rs = (m > 1.0f) ? 1.0f : 0.0f;          // reset from PREV mem
                m = __fsub_rn(__fadd_rn(__fmul_rn(0.95f, m), c), rs);
                bits |= ((m > 1.0f) ? 1u : 0u) << st;
            }
            masks_g[(size_t)(row0 + r) * NHP + u] = bits;           // coalesced (lane=u)
        }
    }
}

// ---------------- K2: fc2 + LIF2 -> outputs ----------------
// Thread = (row, step): decode once per h, reuse across 10 outputs (1.2 VALU/bit).
// cur2 staged in LDS; small scan phase per (row,o); coalesced stores.

#define K2_RPB 10

__global__ __launch_bounds__(256) void k2_fc2(
    const uint32_t* __restrict__ masks_g, const float* __restrict__ w2,
    const float* __restrict__ b2, float* __restrict__ out)
{
    __shared__ float w2s[NH][NOUT];              // 20,000 B
    __shared__ float b2s[NOUT];
    __shared__ float c2[K2_RPB][NOUT][STEPS + 1];// 10,400 B

    const int t    = threadIdx.x;
    const int row0 = blockIdx.x * K2_RPB;

    for (int i = t; i < NH * NOUT; i += 256) {
        const int h = i / NOUT, o = i - h * NOUT;
        w2s[h][o] = w2[o * NH + h];
    }
    if (t < NOUT) b2s[t] = b2[t];
    __syncthreads();

    const int rl = t / STEPS;                    // 0..9 for t<250
    const int st = t - rl * STEPS;               // 0..24
    const int row = row0 + rl;

    if (t < K2_RPB * STEPS && row < B_ROWS) {
        float a[NOUT];
#pragma unroll
        for (int o = 0; o < NOUT; ++o) a[o] = 0.f;
        const uint32_t* mrow = masks_g + (size_t)row * NHP;
        for (int h = 0; h < NH; ++h) {
            const float s = (float)((mrow[h] >> st) & 1u);   // 1 decode for 10 outputs
#pragma unroll
            for (int o = 0; o < NOUT; ++o)
                a[o] = fmaf(s, w2s[h][o], a[o]);  // ascending-h chain per (row,o,st)
        }
#pragma unroll
        for (int o = 0; o < NOUT; ++o) c2[rl][o][st] = a[o];
    }
    __syncthreads();

    if (t < K2_RPB * NOUT) {                     // scan phase: (row, o)
        const int r2 = t / NOUT, o = t - r2 * NOUT;
        const int row2 = row0 + r2;
        if (row2 < B_ROWS) {
            float* spk_out = out;
            float* mem_out = out + (size_t)STEPS * B_ROWS * NOUT;
            const size_t base = (size_t)row2 * NOUT + o;
            const float bo = b2s[o];
            float m = 0.f;
#pragma unroll
            for (int s2 = 0; s2 < STEPS; ++s2) {
                const float c  = __fadd_rn(c2[r2][o][s2], bo);   // chain + bias
                const float rs = (m > 1.0f) ? 1.0f : 0.0f;       // reset from PREV mem
                m = __fsub_rn(__fadd_rn(__fmul_rn(0.95f, m), c), rs);
                const size_t idx = (size_t)s2 * (B_ROWS * NOUT) + base;
                spk_out[idx] = (m > 1.0f) ? 1.0f : 0.0f;
                mem_out[idx] = m;
            }
        }
    }
}

extern "C" void kernel_launch(void* const* d_in, const int* in_sizes, int n_in,
                              void* d_out, int out_size, void* d_ws, size_t ws_size,
                              hipStream_t stream)
{
    const float* x  = (const float*)d_in[0];
    const float* w1 = (const float*)d_in[1];
    const float* b1 = (const float*)d_in[2];
    const float* w2 = (const float*)d_in[3];
    const float* b2 = (const float*)d_in[4];
    float* out = (float*)d_out;

    // ws: w1tb 196*2048*4 = 1,605,632 B @ 0; masks 16384*512*4 = 33,554,432 B after
    float*    w1tb    = (float*)d_ws;
    uint32_t* masks_g = (uint32_t*)((char*)d_ws + 1605632);

    k0_wtrans<<<dim3(392), 256, 0, stream>>>(w1, w1tb);
    k1_fc1<<<dim3(B_ROWS / K1_R), 256, 0, stream>>>(x, w1tb, b1, masks_g);
    k2_fc2<<<dim3((B_ROWS + K2_RPB - 1) / K2_RPB), 256, 0, stream>>>(masks_g, w2, b2, out);
}